// Round 3
// baseline (244.063 us; speedup 1.0000x reference)
//
#include <hip/hip_runtime.h>

#define N_FEATURES 4096
#define N_GROUPS   1024
#define BATCH      8192
#define NV4        (N_FEATURES / 4)   // 1024 float4 per row

// Fused kernel. 2048 blocks x 256 threads; one 64-lane wave per row.
//  1. Each wave pre-issues its row's 16 float4 loads into registers
//     (independent of coeff -> HBM traffic starts immediately).
//  2. Block rebuilds coeff[4096] in LDS (zero + gather-scatter with LDS
//     atomics). Side arrays are ~60 KB and L2/L3-resident; the 2048x
//     duplication costs ~4 us aggregate of L2 reads -- hidden behind the
//     in-flight x loads.
//  3. Dot x-registers against LDS coeff, 64-lane shuffle reduce, store.
__global__ __launch_bounds__(256) void fused_kernel(
    const float* __restrict__ x,
    const int* __restrict__ flat_idx,
    const int* __restrict__ seg_ids,
    const float* __restrict__ w_flat,
    const float* __restrict__ diag_w,
    const float* __restrict__ dense_W,
    float* __restrict__ out,
    int total)
{
    __shared__ float s_coeff[N_FEATURES];   // 16 KB

    const int wid  = threadIdx.x >> 6;
    const int lane = threadIdx.x & 63;
    const int row  = (blockIdx.x << 2) + wid;

    // --- 1. pre-issue x loads (16 independent dwordx4 per lane) ---
    const float4* __restrict__ xr = (const float4*)(x + (size_t)row * N_FEATURES);
    float4 xv[16];
#pragma unroll
    for (int k = 0; k < 16; ++k)
        xv[k] = xr[(k << 6) + lane];        // coalesced 1 KiB/wave/issue

    // --- 2. build coeff in LDS ---
    for (int i = threadIdx.x; i < N_FEATURES; i += 256) s_coeff[i] = 0.0f;
    __syncthreads();
    for (int i = threadIdx.x; i < total; i += 256) {
        int g = seg_ids[i];
        float c = w_flat[i] * diag_w[g] * dense_W[g];
        atomicAdd(&s_coeff[flat_idx[i]], c);
    }
    __syncthreads();

    // --- 3. dot + reduce ---
    const float4* sc = (const float4*)s_coeff;
    float acc = 0.0f;
#pragma unroll
    for (int k = 0; k < 16; ++k) {
        float4 cv = sc[(k << 6) + lane];
        acc += xv[k].x * cv.x + xv[k].y * cv.y + xv[k].z * cv.z + xv[k].w * cv.w;
    }

#pragma unroll
    for (int off = 32; off > 0; off >>= 1)
        acc += __shfl_down(acc, off, 64);

    if (lane == 0)
        out[row] = acc;
}

extern "C" void kernel_launch(void* const* d_in, const int* in_sizes, int n_in,
                              void* d_out, int out_size, void* d_ws, size_t ws_size,
                              hipStream_t stream) {
    const float* x        = (const float*)d_in[0];  // [BATCH, N_FEATURES]
    const int*   flat_idx = (const int*)d_in[1];    // [total]
    const int*   seg_ids  = (const int*)d_in[2];    // [total]
    const float* w_flat   = (const float*)d_in[3];  // [total]
    const float* diag_w   = (const float*)d_in[4];  // [N_GROUPS]
    const float* dense_W  = (const float*)d_in[5];  // [N_GROUPS]
    float* out = (float*)d_out;                     // [BATCH] (shape [BATCH,1])
    const int total = in_sizes[1];

    fused_kernel<<<BATCH / 4, 256, 0, stream>>>(x, flat_idx, seg_ids, w_flat,
                                                diag_w, dense_W, out, total);
}

// Round 4
// 204.511 us; speedup vs baseline: 1.1934x; 1.1934x over previous
//
#include <hip/hip_runtime.h>

#define N_FEATURES 4096
#define N_GROUPS   1024
#define BATCH      8192
#define NV4        (N_FEATURES / 4)   // 1024 float4 per row

// Kernel 1: coeff[f] = sum_{i: flat_idx[i]==f} w_flat[i]*diag_w[seg[i]]*dense_W[seg[i]]
// Single block; LDS accumulate, write 4096 floats to d_ws.
__global__ __launch_bounds__(1024) void build_coeff_kernel(
    const int* __restrict__ flat_idx,
    const int* __restrict__ seg_ids,
    const float* __restrict__ w_flat,
    const float* __restrict__ diag_w,
    const float* __restrict__ dense_W,
    float* __restrict__ coeff,
    int total)
{
    __shared__ float s_coeff[N_FEATURES];
    for (int i = threadIdx.x; i < N_FEATURES; i += blockDim.x) s_coeff[i] = 0.0f;
    __syncthreads();
    for (int i = threadIdx.x; i < total; i += blockDim.x) {
        int g = seg_ids[i];
        float c = w_flat[i] * diag_w[g] * dense_W[g];
        atomicAdd(&s_coeff[flat_idx[i]], c);
    }
    __syncthreads();
    for (int i = threadIdx.x; i < N_FEATURES; i += blockDim.x) coeff[i] = s_coeff[i];
}

// Kernel 2: out[b] = dot(x[b,:], coeff).
// One wave per row, NO LDS, NO barrier. coeff (16 KB) is read from global and
// is L1-resident per CU (every wave on the CU touches the same 16 KB).
// xv[16] is an explicit register prefetch burst: 16 independent dwordx4 per
// lane issued back-to-back; __launch_bounds__(256,4) caps VGPR at 128 so the
// compiler can actually keep them live (R3 showed it sinks the loads at
// default occupancy targets -> VGPR 44, burst destroyed).
__global__ __launch_bounds__(256, 4) void gemv_kernel(
    const float* __restrict__ x,
    const float* __restrict__ coeff,
    float* __restrict__ out)
{
    const int wid  = threadIdx.x >> 6;
    const int lane = threadIdx.x & 63;
    const int row  = (blockIdx.x << 2) + wid;

    const float4* __restrict__ xr = (const float4*)(x + (size_t)row * N_FEATURES);
    const float4* __restrict__ c4 = (const float4*)coeff;

    float4 xv[16];
#pragma unroll
    for (int k = 0; k < 16; ++k)
        xv[k] = xr[(k << 6) + lane];       // 16 outstanding dwordx4, coalesced

    float acc = 0.0f;
#pragma unroll
    for (int k = 0; k < 16; ++k) {
        float4 cv = c4[(k << 6) + lane];   // L1-hit after first wave warms it
        acc += xv[k].x * cv.x + xv[k].y * cv.y + xv[k].z * cv.z + xv[k].w * cv.w;
    }

    // 64-lane shuffle reduction
#pragma unroll
    for (int off = 32; off > 0; off >>= 1)
        acc += __shfl_down(acc, off, 64);

    if (lane == 0)
        out[row] = acc;
}

extern "C" void kernel_launch(void* const* d_in, const int* in_sizes, int n_in,
                              void* d_out, int out_size, void* d_ws, size_t ws_size,
                              hipStream_t stream) {
    const float* x        = (const float*)d_in[0];  // [BATCH, N_FEATURES]
    const int*   flat_idx = (const int*)d_in[1];    // [total]
    const int*   seg_ids  = (const int*)d_in[2];    // [total]
    const float* w_flat   = (const float*)d_in[3];  // [total]
    const float* diag_w   = (const float*)d_in[4];  // [N_GROUPS]
    const float* dense_W  = (const float*)d_in[5];  // [N_GROUPS]
    float* out = (float*)d_out;                     // [BATCH] (shape [BATCH,1])
    const int total = in_sizes[1];

    float* coeff = (float*)d_ws;  // N_FEATURES floats of scratch

    build_coeff_kernel<<<1, 1024, 0, stream>>>(flat_idx, seg_ids, w_flat,
                                               diag_w, dense_W, coeff, total);
    gemv_kernel<<<BATCH / 4, 256, 0, stream>>>(x, coeff, out);
}